// Round 8
// baseline (43.834 us; speedup 1.0000x reference)
//
#include <hip/hip_runtime.h>

// AttnCutLoss: loss = -mean_b sum_j log(output[b,j]) * softmax_j(f1(labels[b,:j+1]) / tau)
// f1 at cutoff k (csum c, total t): 2c/(k+t), 0 if t==0.
// s_j = (2*log2e/tau)*c_j/(k_j+t) in [0,~1.52] -> exp2 without max-subtract.
// ln(o) = ln2*log2(o). One wave per row; no __syncthreads in the hot path.
//
// R8: (1) fused final reduction -- per-block partial + one atomicAdd into d_out
//     (d_out zeroed by a 4-byte hipMemsetAsync node); removes the dependent
//     single-block reduce kernel (~4-6us tail).
//     (2) labels loaded NON-TEMPORAL (single-use stream) so they don't evict
//     the output array from Infinity Cache between graph replays.

constexpr int L   = 2048;
constexpr int TPB = 256;                 // 4 waves = 4 rows per block
constexpr float TAU   = 0.95f;
constexpr float LOG2E = 1.4426950408889634f;
constexpr float LN2   = 0.6931471805599453f;

typedef float f32x4 __attribute__((ext_vector_type(4)));

__global__ __launch_bounds__(TPB, 4) void attncut_fused_kernel(
    const float* __restrict__ output,   // [B, L]
    const float* __restrict__ labels,   // [B, L]
    float* __restrict__ loss,           // [1], pre-zeroed
    float invB)
{
    const int wave = threadIdx.x >> 6;
    const int lane = threadIdx.x & 63;
    const int row  = blockIdx.x * 4 + wave;

    const f32x4* lab4 = reinterpret_cast<const f32x4*>(labels + (size_t)row * L) + lane;
    const f32x4* out4 = reinterpret_cast<const f32x4*>(output + (size_t)row * L) + lane;

    // ---- issue all loads up front; labels are non-temporal (single-use) ----
    f32x4 lb[8], ov[8];
#pragma unroll
    for (int c = 0; c < 8; ++c) lb[c] = __builtin_nontemporal_load(lab4 + c * 64);
#pragma unroll
    for (int c = 0; c < 8; ++c) ov[c] = out4[c * 64];

    // ---- labels -> 4-bit nibble per chunk ----
    unsigned nibs = 0u;
#pragma unroll
    for (int c = 0; c < 8; ++c) {
        unsigned b = (unsigned)lb[c][0] | ((unsigned)lb[c][1] << 1)
                   | ((unsigned)lb[c][2] << 2) | ((unsigned)lb[c][3] << 3);
        nibs |= b << (4 * c);
    }

    // ---- pack per-chunk counts (0..4) into 4 words, 16-bit fields ----
    unsigned w[4];
#pragma unroll
    for (int q = 0; q < 4; ++q) {
        unsigned c0 = __popc((nibs >> (8 * q)) & 0xFu);
        unsigned c1 = __popc((nibs >> (8 * q + 4)) & 0xFu);
        w[q] = c0 | (c1 << 16);
    }

    // ---- 4 packed inclusive wave-scans (independent chains) ----
#pragma unroll
    for (int d = 1; d < 64; d <<= 1) {
#pragma unroll
        for (int q = 0; q < 4; ++q) {
            unsigned n = __shfl_up(w[q], d, 64);
            if (lane >= d) w[q] += n;
        }
    }

    // ---- chunk totals (lane 63) and per-lane exclusive prefixes ----
    float T[8], E[8];
#pragma unroll
    for (int q = 0; q < 4; ++q) {
        unsigned tw = __shfl(w[q], 63, 64);
        unsigned own0 = __popc((nibs >> (8 * q)) & 0xFu);
        unsigned own1 = __popc((nibs >> (8 * q + 4)) & 0xFu);
        T[2 * q]     = (float)(tw & 0xFFFFu);
        T[2 * q + 1] = (float)(tw >> 16);
        E[2 * q]     = (float)((w[q] & 0xFFFFu) - own0);
        E[2 * q + 1] = (float)((w[q] >> 16) - own1);
    }
    const float total = ((T[0] + T[1]) + (T[2] + T[3])) + ((T[4] + T[5]) + (T[6] + T[7]));

    const float K2 = (total > 0.f) ? (2.f * LOG2E / TAU) : 0.f;

    // ---- main loop over chunks ----
    float Z = 0.f, Wd = 0.f;
    float off = 0.f;
#pragma unroll
    for (int c = 0; c < 8; ++c) {
        float cf = off + E[c];
        const unsigned nib = (nibs >> (4 * c)) & 0xFu;
        const float kb = total + (float)(c * 256 + 4 * lane);

        cf += (float)(nib & 1u);
        float e0 = __builtin_amdgcn_exp2f((K2 * cf) * __builtin_amdgcn_rcpf(kb + 1.f));
        Z += e0;  Wd = fmaf(__builtin_amdgcn_logf(ov[c][0]), e0, Wd);

        cf += (float)((nib >> 1) & 1u);
        float e1 = __builtin_amdgcn_exp2f((K2 * cf) * __builtin_amdgcn_rcpf(kb + 2.f));
        Z += e1;  Wd = fmaf(__builtin_amdgcn_logf(ov[c][1]), e1, Wd);

        cf += (float)((nib >> 2) & 1u);
        float e2 = __builtin_amdgcn_exp2f((K2 * cf) * __builtin_amdgcn_rcpf(kb + 3.f));
        Z += e2;  Wd = fmaf(__builtin_amdgcn_logf(ov[c][2]), e2, Wd);

        cf += (float)((nib >> 3) & 1u);
        float e3 = __builtin_amdgcn_exp2f((K2 * cf) * __builtin_amdgcn_rcpf(kb + 4.f));
        Z += e3;  Wd = fmaf(__builtin_amdgcn_logf(ov[c][3]), e3, Wd);

        off += T[c];
    }

    // ---- wave reduce Z, Wd ----
#pragma unroll
    for (int d = 32; d; d >>= 1) {
        Z  += __shfl_xor(Z, d, 64);
        Wd += __shfl_xor(Wd, d, 64);
    }

    // ---- block partial (4 rows) -> single atomicAdd ----
    __shared__ float part[4];
    if (lane == 0) part[wave] = -LN2 * Wd / Z;
    __syncthreads();
    if (threadIdx.x == 0) {
        float p = (part[0] + part[1]) + (part[2] + part[3]);
        atomicAdd(loss, p * invB);
    }
}

extern "C" void kernel_launch(void* const* d_in, const int* in_sizes, int n_in,
                              void* d_out, int out_size, void* d_ws, size_t ws_size,
                              hipStream_t stream) {
    const float* output = (const float*)d_in[0];   // [B, L, 1] fp32
    const float* labels = (const float*)d_in[1];   // [B, L]    fp32
    const int B = in_sizes[1] / L;                 // 8192

    hipMemsetAsync(d_out, 0, sizeof(float), stream);
    attncut_fused_kernel<<<B / 4, TPB, 0, stream>>>(output, labels,
                                                    (float*)d_out, 1.0f / (float)B);
}

// Round 9
// 28.202 us; speedup vs baseline: 1.5543x; 1.5543x over previous
//
#include <hip/hip_runtime.h>

// AttnCutLoss: loss = -mean_b sum_j log(output[b,j]) * softmax_j(f1(labels[b,:j+1]) / tau)
// f1 at cutoff k (csum c, total t): 2c/(k+t), 0 if t==0.
// s_j = (2*log2e/tau)*c_j/(k_j+t) in [0,~1.52] -> exp2 without max-subtract.
// ln(o) = ln2*log2(o). One wave per row; coalesced float4; hw rcp/exp2/log2.
//
// R9: R8's fused row kernel (best measured) but NO memset node: each block
// writes its partial (pre-scaled by 1/B) to d_ws[bid] -- every slot written
// every call, so no zeroing -- and a 1-block micro-kernel sums 2048 partials.

constexpr int L   = 2048;
constexpr int TPB = 256;                 // 4 waves = 4 rows per block
constexpr float TAU   = 0.95f;
constexpr float LOG2E = 1.4426950408889634f;
constexpr float LN2   = 0.6931471805599453f;

typedef float f32x4 __attribute__((ext_vector_type(4)));

__global__ __launch_bounds__(TPB, 4) void attncut_row_kernel(
    const float* __restrict__ output,   // [B, L]
    const float* __restrict__ labels,   // [B, L]
    float* __restrict__ partial,        // [gridDim.x]
    float invB)
{
    const int wave = threadIdx.x >> 6;
    const int lane = threadIdx.x & 63;
    const int row  = blockIdx.x * 4 + wave;

    const f32x4* lab4 = reinterpret_cast<const f32x4*>(labels + (size_t)row * L) + lane;
    const f32x4* out4 = reinterpret_cast<const f32x4*>(output + (size_t)row * L) + lane;

    // ---- loads up front; labels non-temporal (single-use stream) ----
    f32x4 lb[8], ov[8];
#pragma unroll
    for (int c = 0; c < 8; ++c) lb[c] = __builtin_nontemporal_load(lab4 + c * 64);
#pragma unroll
    for (int c = 0; c < 8; ++c) ov[c] = out4[c * 64];

    // ---- labels -> 4-bit nibble per chunk ----
    unsigned nibs = 0u;
#pragma unroll
    for (int c = 0; c < 8; ++c) {
        unsigned b = (unsigned)lb[c][0] | ((unsigned)lb[c][1] << 1)
                   | ((unsigned)lb[c][2] << 2) | ((unsigned)lb[c][3] << 3);
        nibs |= b << (4 * c);
    }

    // ---- pack per-chunk counts (0..4) into 4 words, 16-bit fields ----
    unsigned w[4];
#pragma unroll
    for (int q = 0; q < 4; ++q) {
        unsigned c0 = __popc((nibs >> (8 * q)) & 0xFu);
        unsigned c1 = __popc((nibs >> (8 * q + 4)) & 0xFu);
        w[q] = c0 | (c1 << 16);
    }

    // ---- 4 packed inclusive wave-scans ----
#pragma unroll
    for (int d = 1; d < 64; d <<= 1) {
#pragma unroll
        for (int q = 0; q < 4; ++q) {
            unsigned n = __shfl_up(w[q], d, 64);
            if (lane >= d) w[q] += n;
        }
    }

    // ---- chunk totals and per-lane exclusive prefixes ----
    float T[8], E[8];
#pragma unroll
    for (int q = 0; q < 4; ++q) {
        unsigned tw = __shfl(w[q], 63, 64);
        unsigned own0 = __popc((nibs >> (8 * q)) & 0xFu);
        unsigned own1 = __popc((nibs >> (8 * q + 4)) & 0xFu);
        T[2 * q]     = (float)(tw & 0xFFFFu);
        T[2 * q + 1] = (float)(tw >> 16);
        E[2 * q]     = (float)((w[q] & 0xFFFFu) - own0);
        E[2 * q + 1] = (float)((w[q] >> 16) - own1);
    }
    const float total = ((T[0] + T[1]) + (T[2] + T[3])) + ((T[4] + T[5]) + (T[6] + T[7]));

    const float K2 = (total > 0.f) ? (2.f * LOG2E / TAU) : 0.f;

    // ---- main loop over chunks ----
    float Z = 0.f, Wd = 0.f;
    float off = 0.f;
#pragma unroll
    for (int c = 0; c < 8; ++c) {
        float cf = off + E[c];
        const unsigned nib = (nibs >> (4 * c)) & 0xFu;
        const float kb = total + (float)(c * 256 + 4 * lane);

        cf += (float)(nib & 1u);
        float e0 = __builtin_amdgcn_exp2f((K2 * cf) * __builtin_amdgcn_rcpf(kb + 1.f));
        Z += e0;  Wd = fmaf(__builtin_amdgcn_logf(ov[c][0]), e0, Wd);

        cf += (float)((nib >> 1) & 1u);
        float e1 = __builtin_amdgcn_exp2f((K2 * cf) * __builtin_amdgcn_rcpf(kb + 2.f));
        Z += e1;  Wd = fmaf(__builtin_amdgcn_logf(ov[c][1]), e1, Wd);

        cf += (float)((nib >> 2) & 1u);
        float e2 = __builtin_amdgcn_exp2f((K2 * cf) * __builtin_amdgcn_rcpf(kb + 3.f));
        Z += e2;  Wd = fmaf(__builtin_amdgcn_logf(ov[c][2]), e2, Wd);

        cf += (float)((nib >> 3) & 1u);
        float e3 = __builtin_amdgcn_exp2f((K2 * cf) * __builtin_amdgcn_rcpf(kb + 4.f));
        Z += e3;  Wd = fmaf(__builtin_amdgcn_logf(ov[c][3]), e3, Wd);

        off += T[c];
    }

    // ---- wave reduce Z, Wd ----
#pragma unroll
    for (int d = 32; d; d >>= 1) {
        Z  += __shfl_xor(Z, d, 64);
        Wd += __shfl_xor(Wd, d, 64);
    }

    // ---- block partial (4 rows), pre-scaled; unconditional write, no zeroing ----
    __shared__ float part[4];
    if (lane == 0) part[wave] = -LN2 * Wd / Z;
    __syncthreads();
    if (threadIdx.x == 0) {
        float p = (part[0] + part[1]) + (part[2] + part[3]);
        partial[blockIdx.x] = p * invB;
    }
}

__global__ __launch_bounds__(TPB) void attncut_final_kernel(
    const float* __restrict__ partial, float* __restrict__ out, int n)
{
    const int t = threadIdx.x;
    const float4* p4 = reinterpret_cast<const float4*>(partial);
    float s = 0.f;
#pragma unroll
    for (int i = t; i < 512; i += TPB) {           // n = 2048 -> 512 float4
        float4 v = p4[i];
        s += (v.x + v.y) + (v.z + v.w);
    }
#pragma unroll
    for (int d = 32; d; d >>= 1) s += __shfl_xor(s, d, 64);
    __shared__ float ws[4];
    if ((t & 63) == 0) ws[t >> 6] = s;
    __syncthreads();
    if (t == 0) out[0] = (ws[0] + ws[1]) + (ws[2] + ws[3]);
}

extern "C" void kernel_launch(void* const* d_in, const int* in_sizes, int n_in,
                              void* d_out, int out_size, void* d_ws, size_t ws_size,
                              hipStream_t stream) {
    const float* output = (const float*)d_in[0];   // [B, L, 1] fp32
    const float* labels = (const float*)d_in[1];   // [B, L]    fp32
    const int B = in_sizes[1] / L;                 // 8192
    const int blocks = B / 4;                      // 2048

    float* partial = (float*)d_ws;                 // 2048 floats, all written each call

    attncut_row_kernel<<<blocks, TPB, 0, stream>>>(output, labels, partial, 1.0f / (float)B);
    attncut_final_kernel<<<1, TPB, 0, stream>>>(partial, (float*)d_out, blocks);
}